// Round 4
// baseline (314.714 us; speedup 1.0000x reference)
//
#include <hip/hip_runtime.h>
#include <math.h>

#define H      128
#define LNUM   5
#define ONUM   5
#define BATCH  16
#define NPTS   50000
#define TP     128      // points per trunk block (4 waves x 32-feat slices)
#define XROW   136      // halfs per xs row: 128+8 pad; 68 dwords == 4 mod 32 -> same 2-way-min
                        // bank pattern as the known-good 152 (76 == 12 mod 32), but 16B-aligned rows

#define K2LOG2E 2.8853900817779268f   // 2*log2(e): tanh arg -> exp2 arg

typedef _Float16      half8    __attribute__((ext_vector_type(8)));
typedef float         floatx4  __attribute__((ext_vector_type(4)));
typedef float         floatx2  __attribute__((ext_vector_type(2)));
typedef unsigned int  uint2v   __attribute__((ext_vector_type(2)));
typedef unsigned int  uint4v   __attribute__((ext_vector_type(4)));
typedef unsigned short ushort8_t __attribute__((ext_vector_type(8)));

static __device__ __forceinline__ unsigned short f2h(float f) {
    _Float16 h = (_Float16)f;                       // v_cvt_f16_f32 (RNE)
    return __builtin_bit_cast(unsigned short, h);
}
static __device__ __forceinline__ unsigned int packh(float a, float b) {
    return (unsigned int)f2h(a) | ((unsigned int)f2h(b) << 16);   // RNE pair
}

// ============ fused branch + weight fold: grid (16, 6), 512 thr (unchanged, known-good) ============
__global__ __launch_bounds__(512)
void fold_kernel(const float* __restrict__ params,
                 const float* __restrict__ bW0, const float* __restrict__ bb0,
                 const float* __restrict__ bWh, const float* __restrict__ bbh,
                 const float* __restrict__ balpha,
                 const float* __restrict__ bWf, const float* __restrict__ bbf,
                 const float* __restrict__ tW0, const float* __restrict__ tb0,
                 const float* __restrict__ tWh, const float* __restrict__ tbh,
                 const float* __restrict__ tWf, const float* __restrict__ talpha,
                 const float* __restrict__ tbf,
                 unsigned short* __restrict__ w0s, unsigned short* __restrict__ whs,
                 unsigned short* __restrict__ wcomb, float* __restrict__ bcomb,
                 float* __restrict__ binit) {
    const int b = blockIdx.x, l = blockIdx.y, t = threadIdx.x;
    __shared__ float hbuf[H];
    __shared__ float Sneed[H];
    __shared__ float pbuf[8];
    __shared__ float zl_sh[ONUM][H];
    if (t < 8) pbuf[t] = params[b * 8 + t];
    __syncthreads();

    float scum = 0.0f;
    if (t < H) {
        float acc = bb0[t];
        for (int k = 0; k < 8; ++k) acc += pbuf[k] * bW0[k * H + t];
        float h = balpha[t] * tanhf(acc);
        hbuf[t] = h;
        scum = h;
        if (l == 0) Sneed[t] = scum;
    }
    for (int i = 1; i < LNUM; ++i) {
        __syncthreads();
        float hn = 0.0f;
        if (t < H) {
            const float* Wl = bWh + (i - 1) * H * H;
            float a2 = bbh[(i - 1) * H + t];
            for (int k = 0; k < H; ++k) a2 += hbuf[k] * Wl[k * H + t];
            hn = balpha[i * H + t] * tanhf(a2);
        }
        __syncthreads();
        if (t < H) {
            hbuf[t] = hn;
            scum += hn;
            if (i == l) Sneed[t] = scum;
        }
    }
    __syncthreads();

    if (l == 5) {
        for (int idx = t; idx < ONUM * H; idx += 512) {
            int o = idx >> 7, hh = idx & 127;
            float z = bbf[o * H + hh];
            for (int k = 0; k < H; ++k) z += hbuf[k] * bWf[k * (H * ONUM) + o * H + hh];
            zl_sh[o][hh] = z;
        }
        __syncthreads();
        for (int j = t; j < 16 * H; j += 512) {
            int o = j >> 7, f = j & 127;
            float v = 0.0f;
            if (o < ONUM) {
                const float* wfr = tWf + f * H;
                float s = 0.0f;
                for (int h = 0; h < H; ++h) s += wfr[h] * zl_sh[o][h];
                v = talpha[4 * H + f] * s;
            }
            wcomb[b * 16 * H + j] = f2h(v);
        }
        if (t < 16) {
            float v = 0.0f;
            if (t < ONUM)
                for (int h = 0; h < H; ++h) v += tbf[h] * zl_sh[t][h];
            bcomb[b * 16 + t] = v;
        }
    } else if (l == 0) {
        if (t < H) binit[(b * LNUM + 0) * H + t] = K2LOG2E * Sneed[t] * tb0[t];
        unsigned int* dst = (unsigned int*)(w0s + b * H * 32);
        for (int j = t; j < H * 16; j += 512) {
            int f = j >> 4, k0 = (j & 15) << 1;
            float s = K2LOG2E * Sneed[f];
            float v0 = (k0 < 3)     ? s * tW0[k0 * H + f]       : 0.0f;
            float v1 = (k0 + 1 < 3) ? s * tW0[(k0 + 1) * H + f] : 0.0f;
            dst[j] = packh(v0, v1);
        }
    } else {
        if (t < H) binit[(b * LNUM + l) * H + t] = K2LOG2E * Sneed[t] * tbh[(l - 1) * H + t];
        const float* Wsrc = tWh + (l - 1) * H * H;
        unsigned int* dst = (unsigned int*)(whs + (b * 4 + (l - 1)) * H * H);
        for (int j = t; j < H * H / 2; j += 512) {
            int f = j >> 6, k0 = (j & 63) << 1;
            float s = K2LOG2E * Sneed[f];
            dst[j] = packh(s * Wsrc[k0 * H + f] * talpha[(l - 1) * H + k0],
                           s * Wsrc[(k0 + 1) * H + f] * talpha[(l - 1) * H + k0 + 1]);
        }
    }
}

// ============ trunk R13: R12 schedule + ping-pong xs + packed-f32 epilogue ============
// R10/R11 lesson: do NOT reorder the wave program; R13 keeps R12's exact op order.
// Changes:
//   (1) PING-PONG xs[2]: epilogue of layer l writes the OTHER buffer than the MFMA
//       read -> WAR hazard renamed away -> mid-layer barrier deleted. 11 -> 6 barriers.
//       XROW 152->136 so 2 buffers = 69632 B -> 2 blocks/CU (R12 showed 2.5 vs 3
//       blocks/CU is perf-neutral). Bank pattern identical (68 dw == 4 mod 32: 2-way-min).
//   (2) packed-f32 epilogue: (e+1) and (1-2rc) as float2 vector ops -> v_pk_add_f32 /
//       v_pk_fma_f32, halving non-trans VALU insts in the tanh. IEEE-identical.
//   (3) __launch_bounds__(256,2): required by LDS; 256-reg budget also lets the
//       allocator keep acc in VGPRs (kills ~320 v_accvgpr_read/wave if taken).
__global__ __launch_bounds__(256, 2)
void trunk_kernel(const float* __restrict__ coords,
                  const unsigned short* __restrict__ w0s,
                  const unsigned short* __restrict__ whs,
                  const float* __restrict__ binit,
                  const unsigned short* __restrict__ wcomb,
                  const float* __restrict__ bcomb,
                  float* __restrict__ out) {
    const int b    = blockIdx.y;
    const int n0   = blockIdx.x * TP;
    const int tid  = threadIdx.x;
    const int lane = tid & 63;
    const int w    = tid >> 6;        // wave 0..3
    const int q    = lane >> 4;       // quad 0..3
    const int c    = lane & 15;
    const int mq   = w * 32;          // wave's feature quarter (M); every wave covers all 128 pts

    __shared__ unsigned short xs[2][TP * XROW];   // 2 x 34816 B = 69632 B -> 2 blocks/CU

    // ---- stage coords into xs[0][p][0..31] (fp16, zero-padded K) ----
    int valid = NPTS - n0; if (valid > TP) valid = TP;
    {
        int p = tid >> 1, hh = tid & 1;
        if (hh == 0) {
            float c0 = 0.f, c1 = 0.f, c2 = 0.f;
            if (p < valid) {
                const float* cp = coords + ((size_t)b * NPTS + n0 + p) * 3;
                c0 = cp[0]; c1 = cp[1]; c2 = cp[2];
            }
            uint4v z;
            z.x = __builtin_bit_cast(unsigned int, __builtin_amdgcn_cvt_pkrtz(c0, c1));
            z.y = __builtin_bit_cast(unsigned int, __builtin_amdgcn_cvt_pkrtz(c2, 0.0f));
            z.z = 0; z.w = 0;
            *(uint4v*)&xs[0][p * XROW + 0] = z;                 // k 0..7
            uint4v zz = {0, 0, 0, 0};
            *(uint4v*)&xs[0][p * XROW + 8] = zz;                // k 8..15
        } else {
            uint4v zz = {0, 0, 0, 0};
            *(uint4v*)&xs[0][p * XROW + 16] = zz;               // k 16..31
            *(uint4v*)&xs[0][p * XROW + 24] = zz;
        }
    }
    __syncthreads();

    floatx4 acc[2][8];

    // packed tanh: exp2 (trans, scalar) + pk_add + rcp (trans, scalar) + pk_fma
    auto tanh2 = [](floatx2 x) -> floatx2 {
        floatx2 e;
        e[0] = __builtin_amdgcn_exp2f(x[0]);
        e[1] = __builtin_amdgcn_exp2f(x[1]);
        floatx2 d = e + 1.0f;                                   // v_pk_add_f32
        floatx2 rc;
        rc[0] = __builtin_amdgcn_rcpf(d[0]);
        rc[1] = __builtin_amdgcn_rcpf(d[1]);
        floatx2 m2 = {-2.0f, -2.0f}, one = {1.0f, 1.0f};
        return __builtin_elementwise_fma(m2, rc, one);          // v_pk_fma_f32
    };

    // epilogue: tanh + f16 pack + write to dst buffer
    auto epi = [&](unsigned short* dst) {
        #pragma unroll
        for (int mt = 0; mt < 2; ++mt) {
            int f0 = mq + mt * 16 + q * 4;
            #pragma unroll
            for (int nt = 0; nt < 8; ++nt) {
                int pt = nt * 16 + c;
                floatx4 v = acc[mt][nt];
                floatx2 lo = {v[0], v[1]}, hi = {v[2], v[3]};
                lo = tanh2(lo);
                hi = tanh2(hi);
                uint2v u;
                u.x = __builtin_bit_cast(unsigned int, __builtin_amdgcn_cvt_pkrtz(lo[0], lo[1]));
                u.y = __builtin_bit_cast(unsigned int, __builtin_amdgcn_cvt_pkrtz(hi[0], hi[1]));
                *(uint2v*)&dst[pt * XROW + f0] = u;
            }
        }
    };

    // ================= layer 0: coords (K=32, folded W0), bias via C-operand =================
    // reads xs[0]; epilogue writes xs[1] (no intra-layer barrier needed)
    {
        const unsigned short* w0b = w0s + b * H * 32;
        const float* bi0 = &binit[(b * LNUM + 0) * H];
        half8 af[2];
        floatx4 bi4[2];
        #pragma unroll
        for (int mt = 0; mt < 2; ++mt) {
            af[mt] = __builtin_bit_cast(half8,
                *(const ushort8_t*)&w0b[(mq + mt * 16 + c) * 32 + q * 8]);
            bi4[mt] = *(const floatx4*)&bi0[mq + mt * 16 + q * 4];
        }
        __builtin_amdgcn_s_setprio(1);
        #pragma unroll
        for (int nt = 0; nt < 8; ++nt) {
            half8 bfr = __builtin_bit_cast(half8,
                *(const ushort8_t*)&xs[0][(nt * 16 + c) * XROW + q * 8]);
            #pragma unroll
            for (int mt = 0; mt < 2; ++mt)
                acc[mt][nt] = __builtin_amdgcn_mfma_f32_16x16x32_f16(af[mt], bfr, bi4[mt], 0, 0, 0);
        }
        __builtin_amdgcn_s_setprio(0);
    }
    epi(&xs[1][0]);
    __syncthreads();                              // layer-0 output (xs[1]) visible

    // ================= hidden layers 1..4 (folded Wh), ping-pong =================
    for (int l = 1; l <= 4; ++l) {
        const int rb = l & 1;                     // l1 reads xs[1], l2 reads xs[0], ...
        const unsigned short* wl = whs + (b * 4 + (l - 1)) * H * H;
        const float* bi = &binit[(b * LNUM + l) * H];
        floatx4 bi4[2];
        #pragma unroll
        for (int mt = 0; mt < 2; ++mt)
            bi4[mt] = *(const floatx4*)&bi[mq + mt * 16 + q * 4];
        const unsigned short* src = &xs[rb][0];
        __builtin_amdgcn_s_setprio(1);
        #pragma unroll
        for (int s = 0; s < 4; ++s) {
            half8 af[2];
            #pragma unroll
            for (int mt = 0; mt < 2; ++mt)
                af[mt] = __builtin_bit_cast(half8,
                    *(const ushort8_t*)&wl[(mq + mt * 16 + c) * H + s * 32 + q * 8]);
            #pragma unroll
            for (int nt = 0; nt < 8; ++nt) {
                half8 bfr = __builtin_bit_cast(half8,
                    *(const ushort8_t*)&src[(nt * 16 + c) * XROW + s * 32 + q * 8]);
                if (s == 0) {
                    #pragma unroll
                    for (int mt = 0; mt < 2; ++mt)
                        acc[mt][nt] = __builtin_amdgcn_mfma_f32_16x16x32_f16(af[mt], bfr, bi4[mt], 0, 0, 0);
                } else {
                    #pragma unroll
                    for (int mt = 0; mt < 2; ++mt)
                        acc[mt][nt] = __builtin_amdgcn_mfma_f32_16x16x32_f16(af[mt], bfr, acc[mt][nt], 0, 0, 0);
                }
            }
        }
        __builtin_amdgcn_s_setprio(0);
        epi(&xs[1 - rb][0]);                      // write the OTHER buffer
        __syncthreads();                          // layer-l output visible
    }
    // l=4 read xs[0], wrote xs[1]; final einsum reads xs[1]

    // ---- collapsed layer5+einsum: out[b,pt,o] = x4[pt,:] @ Wcomb[o,:] + bcomb[o] ----
    // wave w handles pts [32w, 32w+32)
    {
        floatx4 bc = *(const floatx4*)&bcomb[b * 16 + q * 4];
        floatx4 oacc[2];
        const unsigned short* wc = wcomb + b * 16 * H;
        #pragma unroll
        for (int s = 0; s < 4; ++s) {
            half8 af = __builtin_bit_cast(half8,
                *(const ushort8_t*)&wc[c * H + s * 32 + q * 8]);
            #pragma unroll
            for (int nt = 0; nt < 2; ++nt) {
                half8 bfr = __builtin_bit_cast(half8,
                    *(const ushort8_t*)&xs[1][(w * 32 + nt * 16 + c) * XROW + s * 32 + q * 8]);
                if (s == 0)
                    oacc[nt] = __builtin_amdgcn_mfma_f32_16x16x32_f16(af, bfr, bc, 0, 0, 0);
                else
                    oacc[nt] = __builtin_amdgcn_mfma_f32_16x16x32_f16(af, bfr, oacc[nt], 0, 0, 0);
            }
        }
        #pragma unroll
        for (int nt = 0; nt < 2; ++nt) {
            int pt = n0 + w * 32 + nt * 16 + c;
            if (pt < NPTS) {
                float* op = out + ((size_t)b * NPTS + pt) * ONUM;
                if (q == 0) {
                    op[0] = oacc[nt][0]; op[1] = oacc[nt][1];
                    op[2] = oacc[nt][2]; op[3] = oacc[nt][3];
                } else if (q == 1) {
                    op[4] = oacc[nt][0];
                }
            }
        }
    }
}

extern "C" void kernel_launch(void* const* d_in, const int* in_sizes, int n_in,
                              void* d_out, int out_size, void* d_ws, size_t ws_size,
                              hipStream_t stream) {
    const float* coords       = (const float*)d_in[0];
    const float* params       = (const float*)d_in[1];
    const float* branch_W0    = (const float*)d_in[2];
    const float* branch_b0    = (const float*)d_in[3];
    const float* branch_Wh    = (const float*)d_in[4];
    const float* branch_bh    = (const float*)d_in[5];
    const float* branch_alpha = (const float*)d_in[6];
    const float* branch_Wf    = (const float*)d_in[7];
    const float* branch_bf    = (const float*)d_in[8];
    const float* trunk_W0     = (const float*)d_in[9];
    const float* trunk_b0     = (const float*)d_in[10];
    const float* trunk_Wh     = (const float*)d_in[11];
    const float* trunk_bh     = (const float*)d_in[12];
    const float* trunk_alpha  = (const float*)d_in[13];
    const float* trunk_Wf     = (const float*)d_in[14];
    const float* trunk_bf     = (const float*)d_in[15];
    float* out = (float*)d_out;

    // workspace layout (256B-aligned offsets)
    char* ws = (char*)d_ws;
    float*          binit = (float*)(ws + 0);                 // 16*5*128 f32   = 40960
    unsigned short* wcomb = (unsigned short*)(ws + 40960);    // 16*16*128 f16  = 65536
    float*          bcomb = (float*)(ws + 106496);            // 16*16 f32      = 1024
    unsigned short* w0s   = (unsigned short*)(ws + 107520);   // 16*128*32 f16  = 131072
    unsigned short* whs   = (unsigned short*)(ws + 238592);   // 16*4*128*128   = 2097152
    // end: 2335744 B

    fold_kernel<<<dim3(BATCH, 6), 512, 0, stream>>>(params, branch_W0, branch_b0,
                                                    branch_Wh, branch_bh, branch_alpha,
                                                    branch_Wf, branch_bf,
                                                    trunk_W0, trunk_b0, trunk_Wh, trunk_bh,
                                                    trunk_Wf, trunk_alpha, trunk_bf,
                                                    w0s, whs, wcomb, bcomb, binit);
    trunk_kernel<<<dim3((NPTS + TP - 1) / TP, BATCH), 256, 0, stream>>>(
        coords, w0s, whs, binit, wcomb, bcomb, out);
}

// Round 5
// 284.793 us; speedup vs baseline: 1.1051x; 1.1051x over previous
//
#include <hip/hip_runtime.h>
#include <math.h>

#define H      128
#define LNUM   5
#define ONUM   5
#define BATCH  16
#define NPTS   50000
#define TP     128      // points per trunk block (4 waves x 32-feat slices)
#define XROW   136      // halfs per xs row: 128+8 pad; 68 dw == 4 mod 32 -> 2-way-min banks
                        // (R13 measured identical SQ_LDS_BANK_CONFLICT as 152); 34816 B/buf
                        // -> 4 blocks/CU LDS-eligible (4x34816=139264 < 160K)

#define K2LOG2E 2.8853900817779268f   // 2*log2(e): tanh arg -> exp2 arg

typedef _Float16      half8    __attribute__((ext_vector_type(8)));
typedef float         floatx4  __attribute__((ext_vector_type(4)));
typedef float         floatx2  __attribute__((ext_vector_type(2)));
typedef unsigned int  uint2v   __attribute__((ext_vector_type(2)));
typedef unsigned int  uint4v   __attribute__((ext_vector_type(4)));
typedef unsigned short ushort8_t __attribute__((ext_vector_type(8)));

static __device__ __forceinline__ unsigned short f2h(float f) {
    _Float16 h = (_Float16)f;                       // v_cvt_f16_f32 (RNE)
    return __builtin_bit_cast(unsigned short, h);
}
static __device__ __forceinline__ unsigned int packh(float a, float b) {
    return (unsigned int)f2h(a) | ((unsigned int)f2h(b) << 16);   // RNE pair
}

// ============ fused branch + weight fold: grid (16, 6), 512 thr (unchanged, known-good) ============
__global__ __launch_bounds__(512)
void fold_kernel(const float* __restrict__ params,
                 const float* __restrict__ bW0, const float* __restrict__ bb0,
                 const float* __restrict__ bWh, const float* __restrict__ bbh,
                 const float* __restrict__ balpha,
                 const float* __restrict__ bWf, const float* __restrict__ bbf,
                 const float* __restrict__ tW0, const float* __restrict__ tb0,
                 const float* __restrict__ tWh, const float* __restrict__ tbh,
                 const float* __restrict__ tWf, const float* __restrict__ talpha,
                 const float* __restrict__ tbf,
                 unsigned short* __restrict__ w0s, unsigned short* __restrict__ whs,
                 unsigned short* __restrict__ wcomb, float* __restrict__ bcomb,
                 float* __restrict__ binit) {
    const int b = blockIdx.x, l = blockIdx.y, t = threadIdx.x;
    __shared__ float hbuf[H];
    __shared__ float Sneed[H];
    __shared__ float pbuf[8];
    __shared__ float zl_sh[ONUM][H];
    if (t < 8) pbuf[t] = params[b * 8 + t];
    __syncthreads();

    float scum = 0.0f;
    if (t < H) {
        float acc = bb0[t];
        for (int k = 0; k < 8; ++k) acc += pbuf[k] * bW0[k * H + t];
        float h = balpha[t] * tanhf(acc);
        hbuf[t] = h;
        scum = h;
        if (l == 0) Sneed[t] = scum;
    }
    for (int i = 1; i < LNUM; ++i) {
        __syncthreads();
        float hn = 0.0f;
        if (t < H) {
            const float* Wl = bWh + (i - 1) * H * H;
            float a2 = bbh[(i - 1) * H + t];
            for (int k = 0; k < H; ++k) a2 += hbuf[k] * Wl[k * H + t];
            hn = balpha[i * H + t] * tanhf(a2);
        }
        __syncthreads();
        if (t < H) {
            hbuf[t] = hn;
            scum += hn;
            if (i == l) Sneed[t] = scum;
        }
    }
    __syncthreads();

    if (l == 5) {
        for (int idx = t; idx < ONUM * H; idx += 512) {
            int o = idx >> 7, hh = idx & 127;
            float z = bbf[o * H + hh];
            for (int k = 0; k < H; ++k) z += hbuf[k] * bWf[k * (H * ONUM) + o * H + hh];
            zl_sh[o][hh] = z;
        }
        __syncthreads();
        for (int j = t; j < 16 * H; j += 512) {
            int o = j >> 7, f = j & 127;
            float v = 0.0f;
            if (o < ONUM) {
                const float* wfr = tWf + f * H;
                float s = 0.0f;
                for (int h = 0; h < H; ++h) s += wfr[h] * zl_sh[o][h];
                v = talpha[4 * H + f] * s;
            }
            wcomb[b * 16 * H + j] = f2h(v);
        }
        if (t < 16) {
            float v = 0.0f;
            if (t < ONUM)
                for (int h = 0; h < H; ++h) v += tbf[h] * zl_sh[t][h];
            bcomb[b * 16 + t] = v;
        }
    } else if (l == 0) {
        if (t < H) binit[(b * LNUM + 0) * H + t] = K2LOG2E * Sneed[t] * tb0[t];
        unsigned int* dst = (unsigned int*)(w0s + b * H * 32);
        for (int j = t; j < H * 16; j += 512) {
            int f = j >> 4, k0 = (j & 15) << 1;
            float s = K2LOG2E * Sneed[f];
            float v0 = (k0 < 3)     ? s * tW0[k0 * H + f]       : 0.0f;
            float v1 = (k0 + 1 < 3) ? s * tW0[(k0 + 1) * H + f] : 0.0f;
            dst[j] = packh(v0, v1);
        }
    } else {
        if (t < H) binit[(b * LNUM + l) * H + t] = K2LOG2E * Sneed[t] * tbh[(l - 1) * H + t];
        const float* Wsrc = tWh + (l - 1) * H * H;
        unsigned int* dst = (unsigned int*)(whs + (b * 4 + (l - 1)) * H * H);
        for (int j = t; j < H * H / 2; j += 512) {
            int f = j >> 6, k0 = (j & 63) << 1;
            float s = K2LOG2E * Sneed[f];
            dst[j] = packh(s * Wsrc[k0 * H + f] * talpha[(l - 1) * H + k0],
                           s * Wsrc[(k0 + 1) * H + f] * talpha[(l - 1) * H + k0 + 1]);
        }
    }
}

// ============ trunk R14: EXACT R9 backbone (known-good 197us) + 2 surgical cuts ============
// Lesson ledger: R10 (chunk pipeline) -53us, R11 (barrier-free) -274us, R13 (ping-pong,
// 2 blocks/CU) -25us. Mechanism that works: many co-resident DE-PHASED blocks covering
// each other's epilogue/MFMA phases. So: R9 program order, R9 barriers, R9 register
// shape (VGPR 64, acc-init loop, no bias-C fusion, no setprio). Only changes:
//   (1) XROW 152->136: same bank-conflict class (R13 measured), LDS 38912->34816
//       -> 4 blocks/CU eligible (was 3-borderline). Occupancy is THE lever here.
//   (2) packed-f32 tanh: (e+1) and (1-2rc) as float2 -> v_pk_add/v_pk_fma, halves
//       non-trans epilogue VALU. Same ops, same order, IEEE-identical results.
__global__ __launch_bounds__(256, 3)
void trunk_kernel(const float* __restrict__ coords,
                  const unsigned short* __restrict__ w0s,
                  const unsigned short* __restrict__ whs,
                  const float* __restrict__ binit,
                  const unsigned short* __restrict__ wcomb,
                  const float* __restrict__ bcomb,
                  float* __restrict__ out) {
    const int b    = blockIdx.y;
    const int n0   = blockIdx.x * TP;
    const int tid  = threadIdx.x;
    const int lane = tid & 63;
    const int w    = tid >> 6;        // wave 0..3
    const int q    = lane >> 4;       // quad 0..3
    const int c    = lane & 15;
    const int mq   = w * 32;          // wave's feature quarter (M); every wave covers all 128 pts

    __shared__ unsigned short xs[TP * XROW];   // 34816 B -> 4 blocks/CU LDS-eligible

    // ---- stage coords into xs[p][0..31] (fp16, zero-padded K) ----
    int valid = NPTS - n0; if (valid > TP) valid = TP;
    {
        int p = tid >> 1, hh = tid & 1;
        if (hh == 0) {
            float c0 = 0.f, c1 = 0.f, c2 = 0.f;
            if (p < valid) {
                const float* cp = coords + ((size_t)b * NPTS + n0 + p) * 3;
                c0 = cp[0]; c1 = cp[1]; c2 = cp[2];
            }
            uint4v z;
            z.x = __builtin_bit_cast(unsigned int, __builtin_amdgcn_cvt_pkrtz(c0, c1));
            z.y = __builtin_bit_cast(unsigned int, __builtin_amdgcn_cvt_pkrtz(c2, 0.0f));
            z.z = 0; z.w = 0;
            *(uint4v*)&xs[p * XROW + 0] = z;                 // k 0..7
            uint4v zz = {0, 0, 0, 0};
            *(uint4v*)&xs[p * XROW + 8] = zz;                // k 8..15
        } else {
            uint4v zz = {0, 0, 0, 0};
            *(uint4v*)&xs[p * XROW + 16] = zz;               // k 16..31
            *(uint4v*)&xs[p * XROW + 24] = zz;
        }
    }
    __syncthreads();

    floatx4 acc[2][8];

    // packed tanh pair: exp2 (trans) -> v_pk_add_f32 -> rcp (trans) -> v_pk_fma_f32
    auto tanh2 = [](floatx2 x) -> floatx2 {
        floatx2 e;
        e[0] = __builtin_amdgcn_exp2f(x[0]);
        e[1] = __builtin_amdgcn_exp2f(x[1]);
        floatx2 d = e + 1.0f;                                   // v_pk_add_f32
        floatx2 rc;
        rc[0] = __builtin_amdgcn_rcpf(d[0]);
        rc[1] = __builtin_amdgcn_rcpf(d[1]);
        floatx2 m2 = {-2.0f, -2.0f}, one = {1.0f, 1.0f};
        return __builtin_elementwise_fma(m2, rc, one);          // v_pk_fma_f32
    };

    // ================= layer 0: coords (K=32, folded W0), bias via C-operand =================
    #pragma unroll
    for (int mt = 0; mt < 2; ++mt) {
        floatx4 bi4 = *(const floatx4*)&binit[(b * LNUM + 0) * H + mq + mt * 16 + q * 4];
        #pragma unroll
        for (int nt = 0; nt < 8; ++nt) acc[mt][nt] = bi4;
    }
    {
        const unsigned short* w0b = w0s + b * H * 32;
        half8 af[2];
        #pragma unroll
        for (int mt = 0; mt < 2; ++mt)
            af[mt] = __builtin_bit_cast(half8,
                *(const ushort8_t*)&w0b[(mq + mt * 16 + c) * 32 + q * 8]);
        #pragma unroll
        for (int nt = 0; nt < 8; ++nt) {
            half8 bfr = __builtin_bit_cast(half8,
                *(const ushort8_t*)&xs[(nt * 16 + c) * XROW + q * 8]);
            #pragma unroll
            for (int mt = 0; mt < 2; ++mt)
                acc[mt][nt] = __builtin_amdgcn_mfma_f32_16x16x32_f16(af[mt], bfr, acc[mt][nt], 0, 0, 0);
        }
    }
    __syncthreads();
    // ---- epilogue layer 0: acc already = 2log2e*S*(Wx+b) ----
    #pragma unroll
    for (int mt = 0; mt < 2; ++mt) {
        int f0 = mq + mt * 16 + q * 4;
        #pragma unroll
        for (int nt = 0; nt < 8; ++nt) {
            int pt = nt * 16 + c;
            floatx4 v = acc[mt][nt];
            floatx2 lo = {v[0], v[1]}, hi = {v[2], v[3]};
            lo = tanh2(lo);
            hi = tanh2(hi);
            uint2v u;
            u.x = __builtin_bit_cast(unsigned int, __builtin_amdgcn_cvt_pkrtz(lo[0], lo[1]));
            u.y = __builtin_bit_cast(unsigned int, __builtin_amdgcn_cvt_pkrtz(hi[0], hi[1]));
            *(uint2v*)&xs[pt * XROW + f0] = u;
        }
    }

    // ================= hidden layers 1..4 (folded Wh) =================
    for (int l = 1; l <= 4; ++l) {
        const unsigned short* wl = whs + (b * 4 + (l - 1)) * H * H;
        #pragma unroll
        for (int mt = 0; mt < 2; ++mt) {
            floatx4 bi4 = *(const floatx4*)&binit[(b * LNUM + l) * H + mq + mt * 16 + q * 4];
            #pragma unroll
            for (int nt = 0; nt < 8; ++nt) acc[mt][nt] = bi4;
        }
        __syncthreads();                          // prev epilogue writes visible
        #pragma unroll
        for (int s = 0; s < 4; ++s) {
            half8 af[2];
            #pragma unroll
            for (int mt = 0; mt < 2; ++mt)
                af[mt] = __builtin_bit_cast(half8,
                    *(const ushort8_t*)&wl[(mq + mt * 16 + c) * H + s * 32 + q * 8]);
            #pragma unroll
            for (int nt = 0; nt < 8; ++nt) {
                half8 bfr = __builtin_bit_cast(half8,
                    *(const ushort8_t*)&xs[(nt * 16 + c) * XROW + s * 32 + q * 8]);
                #pragma unroll
                for (int mt = 0; mt < 2; ++mt)
                    acc[mt][nt] = __builtin_amdgcn_mfma_f32_16x16x32_f16(af[mt], bfr, acc[mt][nt], 0, 0, 0);
            }
        }
        __syncthreads();                          // all xs reads done before overwrite
        #pragma unroll
        for (int mt = 0; mt < 2; ++mt) {
            int f0 = mq + mt * 16 + q * 4;
            #pragma unroll
            for (int nt = 0; nt < 8; ++nt) {
                int pt = nt * 16 + c;
                floatx4 v = acc[mt][nt];
                floatx2 lo = {v[0], v[1]}, hi = {v[2], v[3]};
                lo = tanh2(lo);
                hi = tanh2(hi);
                uint2v u;
                u.x = __builtin_bit_cast(unsigned int, __builtin_amdgcn_cvt_pkrtz(lo[0], lo[1]));
                u.y = __builtin_bit_cast(unsigned int, __builtin_amdgcn_cvt_pkrtz(hi[0], hi[1]));
                *(uint2v*)&xs[pt * XROW + f0] = u;
            }
        }
    }
    __syncthreads();                              // x4 (tanh) ready in xs

    // ---- collapsed layer5+einsum: out[b,pt,o] = x4[pt,:] @ Wcomb[o,:] + bcomb[o] ----
    // wave w handles pts [32w, 32w+32)
    {
        floatx4 bc = *(const floatx4*)&bcomb[b * 16 + q * 4];
        floatx4 oacc[2] = {bc, bc};
        const unsigned short* wc = wcomb + b * 16 * H;
        #pragma unroll
        for (int s = 0; s < 4; ++s) {
            half8 af = __builtin_bit_cast(half8,
                *(const ushort8_t*)&wc[c * H + s * 32 + q * 8]);
            #pragma unroll
            for (int nt = 0; nt < 2; ++nt) {
                half8 bfr = __builtin_bit_cast(half8,
                    *(const ushort8_t*)&xs[(w * 32 + nt * 16 + c) * XROW + s * 32 + q * 8]);
                oacc[nt] = __builtin_amdgcn_mfma_f32_16x16x32_f16(af, bfr, oacc[nt], 0, 0, 0);
            }
        }
        #pragma unroll
        for (int nt = 0; nt < 2; ++nt) {
            int pt = n0 + w * 32 + nt * 16 + c;
            if (pt < NPTS) {
                float* op = out + ((size_t)b * NPTS + pt) * ONUM;
                if (q == 0) {
                    op[0] = oacc[nt][0]; op[1] = oacc[nt][1];
                    op[2] = oacc[nt][2]; op[3] = oacc[nt][3];
                } else if (q == 1) {
                    op[4] = oacc[nt][0];
                }
            }
        }
    }
}

extern "C" void kernel_launch(void* const* d_in, const int* in_sizes, int n_in,
                              void* d_out, int out_size, void* d_ws, size_t ws_size,
                              hipStream_t stream) {
    const float* coords       = (const float*)d_in[0];
    const float* params       = (const float*)d_in[1];
    const float* branch_W0    = (const float*)d_in[2];
    const float* branch_b0    = (const float*)d_in[3];
    const float* branch_Wh    = (const float*)d_in[4];
    const float* branch_bh    = (const float*)d_in[5];
    const float* branch_alpha = (const float*)d_in[6];
    const float* branch_Wf    = (const float*)d_in[7];
    const float* branch_bf    = (const float*)d_in[8];
    const float* trunk_W0     = (const float*)d_in[9];
    const float* trunk_b0     = (const float*)d_in[10];
    const float* trunk_Wh     = (const float*)d_in[11];
    const float* trunk_bh     = (const float*)d_in[12];
    const float* trunk_alpha  = (const float*)d_in[13];
    const float* trunk_Wf     = (const float*)d_in[14];
    const float* trunk_bf     = (const float*)d_in[15];
    float* out = (float*)d_out;

    // workspace layout (256B-aligned offsets)
    char* ws = (char*)d_ws;
    float*          binit = (float*)(ws + 0);                 // 16*5*128 f32   = 40960
    unsigned short* wcomb = (unsigned short*)(ws + 40960);    // 16*16*128 f16  = 65536
    float*          bcomb = (float*)(ws + 106496);            // 16*16 f32      = 1024
    unsigned short* w0s   = (unsigned short*)(ws + 107520);   // 16*128*32 f16  = 131072
    unsigned short* whs   = (unsigned short*)(ws + 238592);   // 16*4*128*128   = 2097152
    // end: 2335744 B

    fold_kernel<<<dim3(BATCH, 6), 512, 0, stream>>>(params, branch_W0, branch_b0,
                                                    branch_Wh, branch_bh, branch_alpha,
                                                    branch_Wf, branch_bf,
                                                    trunk_W0, trunk_b0, trunk_Wh, trunk_bh,
                                                    trunk_Wf, trunk_alpha, trunk_bf,
                                                    w0s, whs, wcomb, bcomb, binit);
    trunk_kernel<<<dim3((NPTS + TP - 1) / TP, BATCH), 256, 0, stream>>>(
        coords, w0s, whs, binit, wcomb, bcomb, out);
}